// Round 3
// baseline (336.424 us; speedup 1.0000x reference)
//
#include <hip/hip_runtime.h>

// 2D gated linear recurrence (SPN-style), scanned over width.
// H[b,c,h,w] = B*X + G1*H[h-1,w-1] + G2*H[h,w-1] + G3*H[h+1,w-1]
// Shapes: [BATCH=16, CH=32, HGT=128, WID=128], fp32, w innermost.
//
// Mapping: one 64-lane wave per (b,c) plane. Lane t owns rows 2t and 2t+1.
// Cross-row coupling handled by two intra-wave shuffles per w-step
// (no LDS, no barriers). float4 loads along w (contiguous) with a
// distance-1 group (4 w-steps) register prefetch.

constexpr int HGT = 128;
constexpr int WID = 128;
constexpr int PLANES = 16 * 32;  // 512

union F4 {
    float4 v;
    float f[4];
};

__global__ __launch_bounds__(64, 1) void spn2d_kernel(
    const float* __restrict__ Xp, const float* __restrict__ Bp,
    const float* __restrict__ G1p, const float* __restrict__ G2p,
    const float* __restrict__ G3p, float* __restrict__ Op)
{
    const int plane = blockIdx.x;          // 0..511
    const int lane  = threadIdx.x & 63;    // 0..63

    const size_t rowbase = ((size_t)plane * HGT + ((size_t)lane << 1)) * WID;

    const float4* x0  = (const float4*)(Xp  + rowbase);
    const float4* x1  = (const float4*)(Xp  + rowbase + WID);
    const float4* b0  = (const float4*)(Bp  + rowbase);
    const float4* b1  = (const float4*)(Bp  + rowbase + WID);
    const float4* a0  = (const float4*)(G1p + rowbase);
    const float4* a1  = (const float4*)(G1p + rowbase + WID);
    const float4* c0  = (const float4*)(G2p + rowbase);
    const float4* c1  = (const float4*)(G2p + rowbase + WID);
    const float4* d0  = (const float4*)(G3p + rowbase);
    const float4* d1  = (const float4*)(G3p + rowbase + WID);
    float4* o0 = (float4*)(Op + rowbase);
    float4* o1 = (float4*)(Op + rowbase + WID);

    constexpr int NG = WID / 4;  // 32 groups of 4 w-steps

    float h0 = 0.f, h1 = 0.f;   // previous-column H for rows 2t, 2t+1

    // Prefetch group 0.
    F4 cx0, cx1, cb0, cb1, ca0, ca1, cc0, cc1, cd0, cd1;
    cx0.v = x0[0]; cx1.v = x1[0];
    cb0.v = b0[0]; cb1.v = b1[0];
    ca0.v = a0[0]; ca1.v = a1[0];
    cc0.v = c0[0]; cc1.v = c1[0];
    cd0.v = d0[0]; cd1.v = d1[0];

    for (int g = 0; g < NG; ++g) {
        // Prefetch next group (redundant re-load of last group on final iter).
        const int gn = (g + 1 < NG) ? (g + 1) : (NG - 1);
        F4 nx0, nx1, nb0, nb1, na0, na1, nc0, nc1, nd0, nd1;
        nx0.v = x0[gn]; nx1.v = x1[gn];
        nb0.v = b0[gn]; nb1.v = b1[gn];
        na0.v = a0[gn]; na1.v = a1[gn];
        nc0.v = c0[gn]; nc1.v = c1[gn];
        nd0.v = d0[gn]; nd1.v = d1[gn];

        F4 ov0, ov1;
        #pragma unroll
        for (int j = 0; j < 4; ++j) {
            // Neighbor values from the PREVIOUS column (h0/h1 not yet updated).
            float up = __shfl_up(h1, 1, 64);    // row 2t-1 (lane t-1's high row)
            float dn = __shfl_down(h0, 1, 64);  // row 2t+2 (lane t+1's low row)
            if (lane == 0)  up = 0.f;           // h=0 boundary
            if (lane == 63) dn = 0.f;           // h=127 boundary

            float nh0 = cb0.f[j] * cx0.f[j] + ca0.f[j] * up
                      + cc0.f[j] * h0       + cd0.f[j] * h1;
            float nh1 = cb1.f[j] * cx1.f[j] + ca1.f[j] * h0
                      + cc1.f[j] * h1       + cd1.f[j] * dn;
            h0 = nh0;
            h1 = nh1;
            ov0.f[j] = h0;
            ov1.f[j] = h1;
        }
        o0[g] = ov0.v;
        o1[g] = ov1.v;

        // Rotate prefetch buffers.
        cx0 = nx0; cx1 = nx1;
        cb0 = nb0; cb1 = nb1;
        ca0 = na0; ca1 = na1;
        cc0 = nc0; cc1 = nc1;
        cd0 = nd0; cd1 = nd1;
    }
}

extern "C" void kernel_launch(void* const* d_in, const int* in_sizes, int n_in,
                              void* d_out, int out_size, void* d_ws, size_t ws_size,
                              hipStream_t stream) {
    const float* X  = (const float*)d_in[0];
    const float* B  = (const float*)d_in[1];
    const float* G1 = (const float*)d_in[2];
    const float* G2 = (const float*)d_in[3];
    const float* G3 = (const float*)d_in[4];
    float* O = (float*)d_out;

    spn2d_kernel<<<dim3(PLANES), dim3(64), 0, stream>>>(X, B, G1, G2, G3, O);
}

// Round 4
// 225.191 us; speedup vs baseline: 1.4939x; 1.4939x over previous
//
#include <hip/hip_runtime.h>

// 2D gated linear recurrence, scanned over width.
// H[b,c,h,w] = B*X + G1*H[h-1,w-1] + G2*H[h,w-1] + G3*H[h+1,w-1]
// [16,32,128,128] fp32, w innermost.
//
// v2: per-wave LDS transpose staging to fix the 4x sub-line write
// amplification seen in v1 (WRITE_SIZE 124MB for a 32MB output).
// One 64-lane wave per plane. Per w-tile (WT=8):
//   - coalesced float4 global loads of [128h x 8w] into registers
//     (double-buffered across tiles),
//   - transpose into padded LDS [w][S=132] (2-way banks everywhere = free),
//   - compute 8 recurrence steps: lane t owns rows 2t/2t+1, float2 LDS
//     reads per array, h+-1 coupling via 2 shuffles/step,
//   - output staged through LDS and stored as coalesced dwordx4.
// No barriers: each block is a single wave owning its LDS.

constexpr int HGT = 128;
constexpr int WID = 128;
constexpr int PLANES = 16 * 32;   // 512
constexpr int WT = 8;             // w-columns per tile
constexpr int NT = WID / WT;      // 16 tiles
constexpr int S  = 132;           // padded h-stride in dwords (132%32==4 -> 2-way banks)
constexpr int ASZ = WT * S;       // 1056 dwords per array slab (1056%32==0)

__global__ __launch_bounds__(64, 1) void spn2d_kernel(
    const float* __restrict__ Xp, const float* __restrict__ Bp,
    const float* __restrict__ G1p, const float* __restrict__ G2p,
    const float* __restrict__ G3p, float* __restrict__ Op)
{
    __shared__ float lds[6 * ASZ];  // 5 inputs + 1 output tile = 25344 B

    const int plane = blockIdx.x;
    const int l = threadIdx.x;      // 0..63
    const size_t pbase = (size_t)plane * HGT * WID;

    const float* __restrict__ src[5] = {Xp, Bp, G1p, G2p, G3p};

    // Per-lane slice geometry for staging (4 float4 per array per lane):
    //   instr i in 0..3: h = 32*i + l/2, w-segment ws = 4*(l&1)
    const int hb = l >> 1;          // 0..31
    const int ws = 4 * (l & 1);     // 0 or 4

    float4 bufA[20], bufB[20];

    // ---- helpers (all indices static after inlining/unroll) ----
    auto load_tile = [&](int t, float4 (&buf)[20]) {
        #pragma unroll
        for (int a = 0; a < 5; ++a) {
            const float* p = src[a] + pbase + (size_t)t * WT + ws;
            #pragma unroll
            for (int i = 0; i < 4; ++i) {
                buf[a * 4 + i] =
                    *(const float4*)(p + (size_t)(32 * i + hb) * WID);
            }
        }
    };

    auto stage_tile = [&](float4 (&buf)[20]) {
        #pragma unroll
        for (int a = 0; a < 5; ++a) {
            #pragma unroll
            for (int i = 0; i < 4; ++i) {
                const int h = 32 * i + hb;
                float4 v = buf[a * 4 + i];
                lds[a * ASZ + (ws + 0) * S + h] = v.x;
                lds[a * ASZ + (ws + 1) * S + h] = v.y;
                lds[a * ASZ + (ws + 2) * S + h] = v.z;
                lds[a * ASZ + (ws + 3) * S + h] = v.w;
            }
        }
    };

    float h0 = 0.f, h1 = 0.f;       // recurrence carry, rows 2l / 2l+1

    auto compute_tile = [&]() {
        #pragma unroll
        for (int w = 0; w < WT; ++w) {
            const int off = w * S + 2 * l;
            const float2 xv = *(const float2*)&lds[0 * ASZ + off];
            const float2 bv = *(const float2*)&lds[1 * ASZ + off];
            const float2 g1 = *(const float2*)&lds[2 * ASZ + off];
            const float2 g2 = *(const float2*)&lds[3 * ASZ + off];
            const float2 g3 = *(const float2*)&lds[4 * ASZ + off];

            float up = __shfl_up(h1, 1, 64);    // H[2l-1, w-1]
            float dn = __shfl_down(h0, 1, 64);  // H[2l+2, w-1]
            if (l == 0)  up = 0.f;
            if (l == 63) dn = 0.f;

            float n0 = bv.x * xv.x + g1.x * up + g2.x * h0 + g3.x * h1;
            float n1 = bv.y * xv.y + g1.y * h0 + g2.y * h1 + g3.y * dn;
            h0 = n0;
            h1 = n1;
            *(float2*)&lds[5 * ASZ + off] = make_float2(h0, h1);
        }
    };

    auto out_stage = [&](int t) {
        float* o = Op + pbase + (size_t)t * WT + ws;
        #pragma unroll
        for (int i = 0; i < 4; ++i) {
            const int h = 32 * i + hb;
            float4 v;
            v.x = lds[5 * ASZ + (ws + 0) * S + h];
            v.y = lds[5 * ASZ + (ws + 1) * S + h];
            v.z = lds[5 * ASZ + (ws + 2) * S + h];
            v.w = lds[5 * ASZ + (ws + 3) * S + h];
            *(float4*)(o + (size_t)h * WID) = v;
        }
    };

    auto tile_body = [&](int t, float4 (&cur)[20], float4 (&nxt)[20]) {
        if (t + 1 < NT) load_tile(t + 1, nxt);  // prefetch next tile
        stage_tile(cur);                        // vmcnt wait + LDS transpose
        compute_tile();                         // lgkm-ordered vs stage
        out_stage(t);                           // lgkm-ordered vs compute
    };

    load_tile(0, bufA);
    for (int t = 0; t < NT; t += 2) {
        tile_body(t,     bufA, bufB);
        tile_body(t + 1, bufB, bufA);
    }
}

extern "C" void kernel_launch(void* const* d_in, const int* in_sizes, int n_in,
                              void* d_out, int out_size, void* d_ws, size_t ws_size,
                              hipStream_t stream) {
    const float* X  = (const float*)d_in[0];
    const float* B  = (const float*)d_in[1];
    const float* G1 = (const float*)d_in[2];
    const float* G2 = (const float*)d_in[3];
    const float* G3 = (const float*)d_in[4];
    float* O = (float*)d_out;

    spn2d_kernel<<<dim3(PLANES), dim3(64), 0, stream>>>(X, B, G1, G2, G3, O);
}

// Round 5
// 205.613 us; speedup vs baseline: 1.6362x; 1.0952x over previous
//
#include <hip/hip_runtime.h>

// 2D gated linear recurrence, scanned over width.
// H[b,c,h,w] = B*X + G1*H[h-1,w-1] + G2*H[h,w-1] + G3*H[h+1,w-1]
// [16,32,128,128] fp32, w innermost.
//
// v3: WT=16 full-line tiles. Each global load/store instruction covers
// 16 complete 64B lines (4 lanes x 16B contiguous per row, 16 rows).
// Fixes v2's 1.69x read amplification (FETCH 270MB vs 160MB compulsory:
// WT=8 used only 32B of each 64B line per access).
// Padded LDS transpose staging ([w][S=132], measured 0 bank conflicts)
// decouples the w-contiguous memory layout from h-parallel compute.
// One 64-lane wave per plane; lane t owns rows 2t/2t+1; h+-1 coupling
// via 2 shuffles/step. No barriers (1 wave per block).

constexpr int HGT = 128;
constexpr int WID = 128;
constexpr int PLANES = 16 * 32;   // 512
constexpr int WT = 16;            // w-columns per tile (64 B per row)
constexpr int NT = WID / WT;      // 8 tiles
constexpr int S  = 132;           // padded h-stride in dwords (2-way banks = free)
constexpr int ASZ = WT * S;       // 2112 dwords per array slab

__global__ __launch_bounds__(64, 1) void spn2d_kernel(
    const float* __restrict__ Xp, const float* __restrict__ Bp,
    const float* __restrict__ G1p, const float* __restrict__ G2p,
    const float* __restrict__ G3p, float* __restrict__ Op)
{
    __shared__ float lds[6 * ASZ];  // 5 inputs + 1 output slab = 50688 B

    const int plane = blockIdx.x;
    const int l = threadIdx.x;      // 0..63
    const size_t pbase = (size_t)plane * HGT * WID;

    const float* __restrict__ src[5] = {Xp, Bp, G1p, G2p, G3p};

    // Full-line staging geometry: 4 lanes per row, 16 rows per instruction.
    //   instr i in 0..7: row h = 16*i + q, w-block wb = 4*(l&3)
    const int q  = l >> 2;          // 0..15
    const int wb = (l & 3) * 4;     // 0,4,8,12

    float4 bufA[40], bufB[40];

    auto load_tile = [&](int t, float4 (&buf)[40]) {
        #pragma unroll
        for (int a = 0; a < 5; ++a) {
            const float* p = src[a] + pbase + (size_t)t * WT + wb;
            #pragma unroll
            for (int i = 0; i < 8; ++i) {
                buf[a * 8 + i] =
                    *(const float4*)(p + (size_t)(16 * i + q) * WID);
            }
        }
    };

    auto stage_tile = [&](float4 (&buf)[40]) {
        #pragma unroll
        for (int a = 0; a < 5; ++a) {
            #pragma unroll
            for (int i = 0; i < 8; ++i) {
                const int h = 16 * i + q;
                float4 v = buf[a * 8 + i];
                // banks: q + 16*((l&3)&1) + const -> exactly 2 lanes/bank (free)
                lds[a * ASZ + (wb + 0) * S + h] = v.x;
                lds[a * ASZ + (wb + 1) * S + h] = v.y;
                lds[a * ASZ + (wb + 2) * S + h] = v.z;
                lds[a * ASZ + (wb + 3) * S + h] = v.w;
            }
        }
    };

    float h0 = 0.f, h1 = 0.f;       // recurrence carry, rows 2l / 2l+1

    auto compute_tile = [&]() {
        #pragma unroll
        for (int w = 0; w < WT; ++w) {
            const int off = w * S + 2 * l;
            const float2 xv = *(const float2*)&lds[0 * ASZ + off];
            const float2 bv = *(const float2*)&lds[1 * ASZ + off];
            const float2 g1 = *(const float2*)&lds[2 * ASZ + off];
            const float2 g2 = *(const float2*)&lds[3 * ASZ + off];
            const float2 g3 = *(const float2*)&lds[4 * ASZ + off];

            float up = __shfl_up(h1, 1, 64);    // H[2l-1, w-1]
            float dn = __shfl_down(h0, 1, 64);  // H[2l+2, w-1]
            if (l == 0)  up = 0.f;
            if (l == 63) dn = 0.f;

            float n0 = bv.x * xv.x + g1.x * up + g2.x * h0 + g3.x * h1;
            float n1 = bv.y * xv.y + g1.y * h0 + g2.y * h1 + g3.y * dn;
            h0 = n0;
            h1 = n1;
            *(float2*)&lds[5 * ASZ + off] = make_float2(h0, h1);
        }
    };

    auto out_stage = [&](int t) {
        float* o = Op + pbase + (size_t)t * WT + wb;
        #pragma unroll
        for (int i = 0; i < 8; ++i) {
            const int h = 16 * i + q;
            float4 v;
            v.x = lds[5 * ASZ + (wb + 0) * S + h];
            v.y = lds[5 * ASZ + (wb + 1) * S + h];
            v.z = lds[5 * ASZ + (wb + 2) * S + h];
            v.w = lds[5 * ASZ + (wb + 3) * S + h];
            *(float4*)(o + (size_t)h * WID) = v;   // 16 full 64B lines/instr
        }
    };

    auto tile_body = [&](int t, float4 (&cur)[40], float4 (&nxt)[40]) {
        if (t + 1 < NT) load_tile(t + 1, nxt);  // prefetch next tile
        stage_tile(cur);                        // vmcnt wait + LDS transpose
        compute_tile();
        out_stage(t);
    };

    load_tile(0, bufA);
    for (int t = 0; t < NT; t += 2) {
        tile_body(t,     bufA, bufB);
        tile_body(t + 1, bufB, bufA);
    }
}

extern "C" void kernel_launch(void* const* d_in, const int* in_sizes, int n_in,
                              void* d_out, int out_size, void* d_ws, size_t ws_size,
                              hipStream_t stream) {
    const float* X  = (const float*)d_in[0];
    const float* B  = (const float*)d_in[1];
    const float* G1 = (const float*)d_in[2];
    const float* G2 = (const float*)d_in[3];
    const float* G3 = (const float*)d_in[4];
    float* O = (float*)d_out;

    spn2d_kernel<<<dim3(PLANES), dim3(64), 0, stream>>>(X, B, G1, G2, G3, O);
}